// Round 13
// baseline (402.241 us; speedup 1.0000x reference)
//
#include <hip/hip_runtime.h>
#include <hip/hip_bf16.h>
#include <hip/hip_cooperative_groups.h>
#include <math.h>

namespace cg = cooperative_groups;

// Problem constants
#define Bc   2
#define Lc   2048
#define Dc   512
#define DIc  1024
#define Nc   16
#define Kc   4
#define Rc   32
#define CKc  31
#define DFFc 2048
#define Mrows (Bc*Lc)   // 4096
#define CHUNK  32
#define NCHUNK 64

typedef __hip_bfloat16 bf16;
typedef short bf16x8 __attribute__((ext_vector_type(8)));
typedef float f32x4  __attribute__((ext_vector_type(4)));

__device__ __forceinline__ float sigmoidf_(float x){ return 1.f/(1.f+expf(-x)); }
__device__ __forceinline__ float siluf_(float x){ return x*sigmoidf_(x); }
__device__ __forceinline__ float softplusf_(float x){ return fmaxf(x,0.f)+log1pf(expf(-fabsf(x))); }
__device__ __forceinline__ float geluf_(float x){
    float x3 = x*x*x;
    return 0.5f*x*(1.f+tanhf(0.7978845608028654f*(x+0.044715f*x3)));
}

// async global -> LDS, 16 bytes/lane; lptr is wave-uniform base (HW adds lane*16)
__device__ __forceinline__ void gload16(const void* g, void* l) {
    __builtin_amdgcn_global_load_lds((const __attribute__((address_space(1))) void*)g,
                                     (__attribute__((address_space(3))) void*)l, 16, 0, 0);
}

// ---------------- LayerNorm (one block per row, D=512); optional f32/bf16 outs ----------------
template<bool WF, bool WB>
__global__ void ln_kernel(const float* __restrict__ in, const float* __restrict__ g,
                          const float* __restrict__ bb, float* __restrict__ outf,
                          bf16* __restrict__ outb, int D) {
    int row = blockIdx.x;
    const float* x = in + (size_t)row * D;
    float s = 0.f, s2 = 0.f;
    for (int i = threadIdx.x; i < D; i += blockDim.x) { float v = x[i]; s += v; s2 += v*v; }
    #pragma unroll
    for (int off = 32; off; off >>= 1) { s += __shfl_down(s, off); s2 += __shfl_down(s2, off); }
    __shared__ float sh[2][4];
    int wave = threadIdx.x >> 6, lane = threadIdx.x & 63;
    if (lane == 0) { sh[0][wave] = s; sh[1][wave] = s2; }
    __syncthreads();
    if (threadIdx.x == 0) {
        float ts = 0.f, ts2 = 0.f;
        int nw = blockDim.x >> 6;
        for (int w = 0; w < nw; ++w) { ts += sh[0][w]; ts2 += sh[1][w]; }
        sh[0][0] = ts; sh[1][0] = ts2;
    }
    __syncthreads();
    float mean = sh[0][0] / D;
    float var  = sh[1][0] / D - mean*mean;
    float rstd = rsqrtf(var + 1e-5f);
    for (int i = threadIdx.x; i < D; i += blockDim.x) {
        float v = (x[i]-mean)*rstd*g[i] + bb[i];
        if (WF) outf[(size_t)row*D + i] = v;
        if (WB) outb[(size_t)row*D + i] = __float2bfloat16(v);
    }
}

// ---------------- merged prep: 8 weight transposes + LN1, one launch ----------------
struct PrepPack {
    const float* W[8]; bf16* Wt[8]; int K[8]; int N[8]; int start[9];
    const float* x; const float* lg; const float* lb; bf16* hb;
    int lnStart;
};

__global__ __launch_bounds__(256) void prep_all(PrepPack p) {
    __shared__ float t[32][33];
    __shared__ float sh[2][4];
    int tb = blockIdx.x, tid = threadIdx.x;
    if (tb < p.lnStart) {
        int wi = 0;
        #pragma unroll
        for (int i = 0; i < 7; ++i) if (tb >= p.start[i+1]) wi = i+1;
        int lt = tb - p.start[wi];
        int K = p.K[wi], N = p.N[wi];
        int ntx = N >> 5;
        int bx = lt % ntx, by = lt / ntx;
        const float* W = p.W[wi];
        bf16* Wt = p.Wt[wi];
        int tx = tid & 31, ty = tid >> 5;
        #pragma unroll
        for (int i = 0; i < 32; i += 8)
            t[ty+i][tx] = W[(size_t)(by*32+ty+i)*N + bx*32+tx];
        __syncthreads();
        #pragma unroll
        for (int i = 0; i < 32; i += 8)
            Wt[(size_t)(bx*32+ty+i)*K + by*32+tx] = __float2bfloat16(t[tx][ty+i]);
    } else {
        int row = tb - p.lnStart;
        const float* xr = p.x + (size_t)row * Dc;
        float s = 0.f, s2 = 0.f;
        for (int i = tid; i < Dc; i += 256) { float v = xr[i]; s += v; s2 += v*v; }
        #pragma unroll
        for (int off = 32; off; off >>= 1) { s += __shfl_down(s, off); s2 += __shfl_down(s2, off); }
        int wave = tid >> 6, lane = tid & 63;
        if (lane == 0) { sh[0][wave] = s; sh[1][wave] = s2; }
        __syncthreads();
        if (tid == 0) {
            float ts = 0.f, ts2 = 0.f;
            for (int w = 0; w < 4; ++w) { ts += sh[0][w]; ts2 += sh[1][w]; }
            sh[0][0] = ts; sh[1][0] = ts2;
        }
        __syncthreads();
        float mean = sh[0][0] / Dc;
        float var  = sh[1][0] / Dc - mean*mean;
        float rstd = rsqrtf(var + 1e-5f);
        for (int i = tid; i < Dc; i += 256)
            p.hb[(size_t)row*Dc + i] = __float2bfloat16((xr[i]-mean)*rstd*p.lg[i] + p.lb[i]);
    }
}

// ---------------- bf16 MFMA GEMM, 2-phase dbuf + global_load_lds + XOR swizzle ----------------
// SPLITK>1: grid.z splits K; raw fp32 partials to outf + z*M*N.
// ZSEL=1: grid.z selects weight-half (Wt += z*N*K) and output-half (out += z*M*N).
template<int BM, int BN, int SPLITK, int ZSEL, int ACT, bool BIAS, bool RES, bool WF32, bool WBF16>
__global__ __launch_bounds__(256) void mgemm(const bf16* __restrict__ A, int lda,
                                             const bf16* __restrict__ Wt,
                                             const float* __restrict__ bias,
                                             const float* __restrict__ res,
                                             float* __restrict__ outf,
                                             bf16* __restrict__ outb,
                                             int M, int N, int K) {
    constexpr int BK = 32;
    constexpr int WM = BM/2, WN = BN/2;
    constexpr int AM = WM/16, AN = WN/16;
    constexpr int AISS = BM/64, BISS = BN/64;
    __shared__ __align__(16) bf16 As[2][BM*BK];
    __shared__ __align__(16) bf16 Bs[2][BN*BK];
    const int tid  = threadIdx.x;
    const int wave = tid >> 6, lane = tid & 63;
    const int r16  = lane & 15, kb = lane >> 4;
    const int gx = gridDim.x;
    const int nwg = gx*gridDim.y;
    const int id  = blockIdx.y*gx + blockIdx.x;
    const int sid = (id & 7)*(nwg >> 3) + (id >> 3);
    const int bm = (sid / gx)*BM, bn = (sid % gx)*BN;
    const int wm = (wave>>1)*WM, wn = (wave&1)*WN;
    const bf16* Wp = Wt;
    float* outfp = outf;
    bf16*  outbp = outb;
    if (ZSEL) {
        Wp += (size_t)blockIdx.z*N*K;
        if (WF32)  outfp += (size_t)blockIdx.z*M*N;
        if (WBF16) outbp += (size_t)blockIdx.z*M*N;
    }
    const int Keff = K / SPLITK;
    const int kz0  = (SPLITK > 1) ? blockIdx.z * Keff : 0;
    f32x4 acc[AM][AN] = {};
    const int nt = Keff / BK;

    auto stage = [&](int buf, int kt) {
        #pragma unroll
        for (int it = 0; it < AISS; ++it) {
            int base = (wave*AISS + it) << 10;
            int Lb   = base + (lane << 4);
            int row  = Lb >> 6;
            int gch  = ((Lb >> 4) & 3) ^ (row & 3);
            gload16(A + (size_t)(bm + row)*lda + kz0 + kt*BK + gch*8, (char*)As[buf] + base);
        }
        #pragma unroll
        for (int it = 0; it < BISS; ++it) {
            int base = (wave*BISS + it) << 10;
            int Lb   = base + (lane << 4);
            int row  = Lb >> 6;
            int gch  = ((Lb >> 4) & 3) ^ (row & 3);
            gload16(Wp + (size_t)(bn + row)*K + kz0 + kt*BK + gch*8, (char*)Bs[buf] + base);
        }
    };

    stage(0, 0);
    __syncthreads();
    for (int t = 0; t < nt; ++t) {
        int cur = t & 1;
        if (t + 1 < nt) stage(cur ^ 1, t + 1);
        bf16x8 af[AM], bfr[AN];
        #pragma unroll
        for (int mi = 0; mi < AM; ++mi) {
            int r = wm + mi*16 + r16;
            af[mi] = *(const bf16x8*)((const char*)As[cur] + r*64 + ((kb ^ (r & 3)) << 4));
        }
        #pragma unroll
        for (int ni = 0; ni < AN; ++ni) {
            int r = wn + ni*16 + r16;
            bfr[ni] = *(const bf16x8*)((const char*)Bs[cur] + r*64 + ((kb ^ (r & 3)) << 4));
        }
        #pragma unroll
        for (int mi = 0; mi < AM; ++mi)
            #pragma unroll
            for (int ni = 0; ni < AN; ++ni)
                acc[mi][ni] = __builtin_amdgcn_mfma_f32_16x16x32_bf16(af[mi], bfr[ni], acc[mi][ni], 0, 0, 0);
        __syncthreads();
    }

    #pragma unroll
    for (int mi = 0; mi < AM; ++mi) {
        #pragma unroll
        for (int ni = 0; ni < AN; ++ni) {
            #pragma unroll
            for (int r = 0; r < 4; ++r) {
                int grow = bm + wm + mi*16 + kb*4 + r;
                int gcol = bn + wn + ni*16 + r16;
                float v = acc[mi][ni][r];
                if (SPLITK > 1) {
                    outf[(size_t)blockIdx.z*M*N + (size_t)grow*N + gcol] = v;
                } else {
                    if (BIAS) v += bias[gcol];
                    if (ACT == 1) v = softplusf_(v);
                    else if (ACT == 2) v = geluf_(v);
                    if (RES) v += res[(size_t)grow*N + gcol];
                    if (WF32)  outfp[(size_t)grow*N + gcol] = v;
                    if (WBF16) outbp[(size_t)grow*N + gcol] = __float2bfloat16(v);
                }
            }
        }
    }
}

// ---------------- wave-split-K GEMM: 64x64 tile, 4 waves each own K/4, NO barriers in K-loop ----------------
template<int ZSEL, int ACT, bool BIAS, bool RES, bool WF32, bool WBF16>
__global__ __launch_bounds__(256) void wgemm(const bf16* __restrict__ A, int lda,
                                             const bf16* __restrict__ Wt,
                                             const float* __restrict__ bias,
                                             const float* __restrict__ res,
                                             float* __restrict__ outf,
                                             bf16* __restrict__ outb,
                                             int M, int N, int K) {
    constexpr int BM = 64, BN = 64, BK = 32;
    __shared__ __align__(16) char lds[65536];
    const int tid  = threadIdx.x;
    const int wave = tid >> 6, lane = tid & 63;
    const int r16  = lane & 15, kb = lane >> 4;
    const int gx = gridDim.x;
    const int nwg = gx*gridDim.y;
    const int id  = blockIdx.y*gx + blockIdx.x;
    const int sid = (id & 7)*(nwg >> 3) + (id >> 3);
    const int bm = (sid / gx)*BM, bn = (sid % gx)*BN;
    const bf16* Wp = Wt;
    float* outfp = outf;
    bf16*  outbp = outb;
    const float* resp = res;
    if (ZSEL) {
        Wp += (size_t)blockIdx.z*N*K;
        if (WF32)  outfp += (size_t)blockIdx.z*M*N;
        if (WBF16) outbp += (size_t)blockIdx.z*M*N;
    }
    const int Kw  = K >> 2;
    const int k0w = wave * Kw;
    const int nt  = Kw / BK;
    char* myL = lds + wave*16384;
    f32x4 acc[4][4] = {};

    auto stage = [&](int buf, int kt) {
        #pragma unroll
        for (int it = 0; it < 4; ++it) {
            int base = it << 10;
            int Lb   = base + (lane << 4);
            int row  = Lb >> 6;
            int gch  = ((Lb >> 4) & 3) ^ (row & 3);
            gload16(A + (size_t)(bm + row)*lda + k0w + kt*BK + gch*8, myL + buf*8192 + base);
        }
        #pragma unroll
        for (int it = 0; it < 4; ++it) {
            int base = it << 10;
            int Lb   = base + (lane << 4);
            int row  = Lb >> 6;
            int gch  = ((Lb >> 4) & 3) ^ (row & 3);
            gload16(Wp + (size_t)(bn + row)*K + k0w + kt*BK + gch*8, myL + buf*8192 + 4096 + base);
        }
    };

    stage(0, 0);
    for (int t = 0; t < nt; ++t) {
        int cur = t & 1;
        if (t + 1 < nt) {
            stage(cur ^ 1, t + 1);
            asm volatile("s_waitcnt vmcnt(8)" ::: "memory");
        } else {
            asm volatile("s_waitcnt vmcnt(0)" ::: "memory");
        }
        __builtin_amdgcn_sched_barrier(0);
        const char* bufA = myL + cur*8192;
        const char* bufB = bufA + 4096;
        bf16x8 af[4], bfr[4];
        #pragma unroll
        for (int mi = 0; mi < 4; ++mi) {
            int r = mi*16 + r16;
            af[mi] = *(const bf16x8*)(bufA + r*64 + ((kb ^ (r & 3)) << 4));
        }
        #pragma unroll
        for (int ni = 0; ni < 4; ++ni) {
            int r = ni*16 + r16;
            bfr[ni] = *(const bf16x8*)(bufB + r*64 + ((kb ^ (r & 3)) << 4));
        }
        #pragma unroll
        for (int mi = 0; mi < 4; ++mi)
            #pragma unroll
            for (int ni = 0; ni < 4; ++ni)
                acc[mi][ni] = __builtin_amdgcn_mfma_f32_16x16x32_bf16(af[mi], bfr[ni], acc[mi][ni], 0, 0, 0);
    }

    __syncthreads();
    float* red = (float*)lds;
    #pragma unroll
    for (int mi = 0; mi < 4; ++mi) {
        #pragma unroll
        for (int ni = 0; ni < 4; ++ni) {
            int row0 = mi*16 + kb*4;
            int col  = ni*16 + r16;
            #pragma unroll
            for (int r = 0; r < 4; ++r)
                red[wave*4096 + (row0+r)*64 + col] = acc[mi][ni][r];
        }
    }
    __syncthreads();
    #pragma unroll
    for (int i = 0; i < 16; ++i) {
        int o = i*256 + tid;
        int row = o >> 6, col = o & 63;
        float v = red[o] + red[4096+o] + red[8192+o] + red[12288+o];
        int grow = bm + row, gcol = bn + col;
        if (BIAS) v += bias[gcol];
        if (ACT == 1) v = softplusf_(v);
        else if (ACT == 2) v = geluf_(v);
        if (RES) v += resp[(size_t)grow*N + gcol];
        if (WF32)  outfp[(size_t)grow*N + gcol] = v;
        if (WBF16) outbp[(size_t)grow*N + gcol] = __float2bfloat16(v);
    }
}

// sum SPLITK partials -> f32 + bf16
__global__ void splitk_combine(const float* __restrict__ part, float* __restrict__ outf,
                               bf16* __restrict__ outb, int n, int parts) {
    int i = blockIdx.x*256 + threadIdx.x;
    if (i >= n) return;
    float s = 0.f;
    for (int p = 0; p < parts; ++p) s += part[(size_t)p*n + i];
    outf[i] = s;
    outb[i] = __float2bfloat16(s);
}

// ---------------- causal depthwise conv K=4 + silu (bf16 in) -> bf16, sliding-window regs ----------------
template<int T>
__global__ __launch_bounds__(256) void causal_conv_silu(const bf16* __restrict__ xi, const float* __restrict__ w,
                                                        const float* __restrict__ bias,
                                                        bf16* __restrict__ xcb) {
    int d  = blockIdx.x*256 + threadIdx.x;
    int b  = blockIdx.y;
    int l0 = blockIdx.z*T;
    const bf16* src = xi + (size_t)b*Lc*DIc + d;
    float wt[Kc];
    #pragma unroll
    for (int k = 0; k < Kc; ++k) wt[k] = w[d*Kc + k];
    float win[T + Kc - 1];
    #pragma unroll
    for (int i = 0; i < T + Kc - 1; ++i) {
        int li = l0 - (Kc-1) + i;
        win[i] = (li >= 0) ? __bfloat162float(src[(size_t)li*DIc]) : 0.f;
    }
    float bv = bias[d];
    size_t obase = (size_t)b*Lc*DIc + (size_t)l0*DIc + d;
    #pragma unroll
    for (int o = 0; o < T; ++o) {
        float acc = bv;
        #pragma unroll
        for (int k = 0; k < Kc; ++k) acc = fmaf(win[o+k], wt[k], acc);
        xcb[obase + (size_t)o*DIc] = __float2bfloat16(siluf_(acc));
    }
}

// ---------------- fused chunked selective scan (cooperative): pass1 + combine + pass3 ----------------
// grid 512 x 256, 0 LDS. xcy: xc in, y out (in place). P gets prefix states in combine.
__global__ __launch_bounds__(256) void scan_fused(const float* __restrict__ delta, bf16* __restrict__ xcy,
                                                  const float* __restrict__ dbl, const bf16* __restrict__ z,
                                                  const float* __restrict__ A_log, const float* __restrict__ Dp,
                                                  float* __restrict__ P, float* __restrict__ H) {
    int dgroup = blockIdx.x & 3;
    int bci = blockIdx.x >> 2;
    int b = bci & 1, chunk = bci >> 1;
    int d = dgroup*256 + threadIdx.x;
    float Av[16];
    #pragma unroll
    for (int j = 0; j < 4; ++j) {
        f32x4 v = *(const f32x4*)(&A_log[d*16 + 4*j]);
        #pragma unroll
        for (int q = 0; q < 4; ++q) Av[4*j+q] = -__expf(v[q]);
    }
    size_t row0 = (size_t)b*Lc + (size_t)chunk*CHUNK;
    size_t pidx = ((size_t)chunk*2048 + (size_t)b*DIc + d) * 16;

    // ---- phase 1: local scan from 0, record P (product) and H (local state) ----
    {
        float h[16], Pl[16];
        #pragma unroll
        for (int n = 0; n < 16; ++n) { h[n] = 0.f; Pl[n] = 1.f; }
        for (int i = 0; i < CHUNK; ++i) {
            size_t rowi = row0 + i;
            float dv  = delta[rowi*DIc + d];
            float xcv = __bfloat162float(xcy[rowi*DIc + d]);
            float dxc = dv*xcv;
            f32x4 B0 = *(const f32x4*)(&dbl[rowi*64 + Rc + 0]);
            f32x4 B1 = *(const f32x4*)(&dbl[rowi*64 + Rc + 4]);
            f32x4 B2 = *(const f32x4*)(&dbl[rowi*64 + Rc + 8]);
            f32x4 B3 = *(const f32x4*)(&dbl[rowi*64 + Rc + 12]);
            float Bv[16];
            #pragma unroll
            for (int q = 0; q < 4; ++q) { Bv[q]=B0[q]; Bv[4+q]=B1[q]; Bv[8+q]=B2[q]; Bv[12+q]=B3[q]; }
            #pragma unroll
            for (int n = 0; n < 16; ++n) {
                float a = __expf(dv*Av[n]);
                h[n] = fmaf(a, h[n], dxc*Bv[n]);
                Pl[n] *= a;
            }
        }
        #pragma unroll
        for (int j = 0; j < 4; ++j) {
            f32x4 vp, vh;
            #pragma unroll
            for (int q = 0; q < 4; ++q) { vp[q] = Pl[4*j+q]; vh[q] = h[4*j+q]; }
            *(f32x4*)(&P[pidx + 4*j]) = vp;
            *(f32x4*)(&H[pidx + 4*j]) = vh;
        }
    }
    cg::this_grid().sync();

    // ---- phase 2: serial combine across chunks (first 128 blocks = 32768 threads) ----
    if (blockIdx.x < 128) {
        int t = blockIdx.x*256 + threadIdx.x;   // (b*DI+d)*16+n
        float hh = 0.f;
        #pragma unroll
        for (int c = 0; c < NCHUNK; ++c) {
            size_t idx = (size_t)c*32768 + t;
            float Pv = P[idx], Hv = H[idx];
            P[idx] = hh;              // hstart for chunk c
            hh = fmaf(Pv, hh, Hv);
        }
    }
    cg::this_grid().sync();

    // ---- phase 3: re-scan from prefix, reduce over n, gate, write y in place ----
    {
        float Dv = Dp[d];
        float h[16];
        #pragma unroll
        for (int j = 0; j < 4; ++j) {
            f32x4 v = *(const f32x4*)(&P[pidx + 4*j]);
            #pragma unroll
            for (int q = 0; q < 4; ++q) h[4*j+q] = v[q];
        }
        for (int i = 0; i < CHUNK; ++i) {
            size_t rowi = row0 + i;
            float dv  = delta[rowi*DIc + d];
            float xcv = __bfloat162float(xcy[rowi*DIc + d]);
            float dxc = dv*xcv;
            f32x4 B0 = *(const f32x4*)(&dbl[rowi*64 + Rc + 0]);
            f32x4 B1 = *(const f32x4*)(&dbl[rowi*64 + Rc + 4]);
            f32x4 B2 = *(const f32x4*)(&dbl[rowi*64 + Rc + 8]);
            f32x4 B3 = *(const f32x4*)(&dbl[rowi*64 + Rc + 12]);
            f32x4 C0 = *(const f32x4*)(&dbl[rowi*64 + Rc + Nc + 0]);
            f32x4 C1 = *(const f32x4*)(&dbl[rowi*64 + Rc + Nc + 4]);
            f32x4 C2 = *(const f32x4*)(&dbl[rowi*64 + Rc + Nc + 8]);
            f32x4 C3 = *(const f32x4*)(&dbl[rowi*64 + Rc + Nc + 12]);
            float Bv[16], Cv[16];
            #pragma unroll
            for (int q = 0; q < 4; ++q) {
                Bv[q]=B0[q]; Bv[4+q]=B1[q]; Bv[8+q]=B2[q]; Bv[12+q]=B3[q];
                Cv[q]=C0[q]; Cv[4+q]=C1[q]; Cv[8+q]=C2[q]; Cv[12+q]=C3[q];
            }
            float s0=0.f, s1=0.f, s2=0.f, s3=0.f;
            #pragma unroll
            for (int n = 0; n < 16; ++n) {
                float a = __expf(dv*Av[n]);
                h[n] = fmaf(a, h[n], dxc*Bv[n]);
            }
            #pragma unroll
            for (int j = 0; j < 4; ++j) {
                s0 = fmaf(h[4*j+0], Cv[4*j+0], s0);
                s1 = fmaf(h[4*j+1], Cv[4*j+1], s1);
                s2 = fmaf(h[4*j+2], Cv[4*j+2], s2);
                s3 = fmaf(h[4*j+3], Cv[4*j+3], s3);
            }
            float contrib = (s0+s1)+(s2+s3);
            float zv = __bfloat162float(z[rowi*DIc + d]);
            xcy[rowi*DIc + d] = __float2bfloat16((contrib + Dv*xcv) * siluf_(zv));
        }
    }
}

// ---------------- fused GLU + symmetric depthwise conv CK=31 + silu (bf16 in) -> bf16 ----------------
template<int T>
__global__ __launch_bounds__(256) void sym_conv_glu_silu(const bf16* __restrict__ c2, const float* __restrict__ w,
                                                         const float* __restrict__ bias, bf16* __restrict__ out) {
    int d  = blockIdx.x*256 + threadIdx.x;
    int b  = blockIdx.y;
    int l0 = blockIdx.z*T;
    const bf16* base = c2 + (size_t)b*Lc*(2*Dc) + d;
    float wt[CKc];
    #pragma unroll
    for (int k = 0; k < CKc; ++k) wt[k] = w[d*CKc + k];
    constexpr int HALF = (CKc-1)/2;
    float win[T + CKc - 1];
    #pragma unroll
    for (int i = 0; i < T + CKc - 1; ++i) {
        int li = l0 - HALF + i;
        if (li >= 0 && li < Lc) {
            float a = __bfloat162float(base[(size_t)li*(2*Dc)]);
            float g = __bfloat162float(base[(size_t)li*(2*Dc) + Dc]);
            win[i] = a * sigmoidf_(g);
        } else win[i] = 0.f;
    }
    float bv = bias[d];
    size_t obase = (size_t)b*Lc*Dc + (size_t)l0*Dc + d;
    #pragma unroll
    for (int o = 0; o < T; ++o) {
        float acc = bv;
        #pragma unroll
        for (int k = 0; k < CKc; ++k) acc = fmaf(win[o+k], wt[k], acc);
        out[obase + (size_t)o*Dc] = __float2bfloat16(siluf_(acc));
    }
}

extern "C" void kernel_launch(void* const* d_in, const int* in_sizes, int n_in,
                              void* d_out, int out_size, void* d_ws, size_t ws_size,
                              hipStream_t stream) {
    const float* x      = (const float*)d_in[0];
    const float* ln_g   = (const float*)d_in[1];
    const float* ln_b   = (const float*)d_in[2];
    const float* W_in   = (const float*)d_in[3];
    const float* conv_w = (const float*)d_in[4];
    const float* conv_b = (const float*)d_in[5];
    const float* W_x    = (const float*)d_in[6];
    const float* W_dt   = (const float*)d_in[7];
    const float* b_dt   = (const float*)d_in[8];
    const float* A_log  = (const float*)d_in[9];
    const float* Dp     = (const float*)d_in[10];
    const float* W_out  = (const float*)d_in[11];
    const float* cm_ln_g= (const float*)d_in[12];
    const float* cm_ln_b= (const float*)d_in[13];
    const float* pw1_w  = (const float*)d_in[14];
    const float* pw1_b  = (const float*)d_in[15];
    const float* dw_w   = (const float*)d_in[16];
    const float* dw_b   = (const float*)d_in[17];
    const float* pw2_w  = (const float*)d_in[18];
    const float* pw2_b  = (const float*)d_in[19];
    const float* ff_W1  = (const float*)d_in[20];
    const float* ff_b1  = (const float*)d_in[21];
    const float* ff_W2  = (const float*)d_in[22];
    const float* ff_b2  = (const float*)d_in[23];
    float* out = (float*)d_out;
    float* ws  = (float*)d_ws;

    // ---- workspace layout (float offsets) ----
    float* A_  = ws;                 // xi_bf16+z_bf16 (16MB) -> part(2M fl)/c2_bf16
    float* A2_ = ws + 4194304;       // P (2M) + H (2M)
    float* B_  = ws + 8388608;       // g1_bf16
    float* C_  = ws + 12582912;      // dbl f32 (M x 64)
    float* D_  = ws + 12845056;      // delta -> m (2M)
    float* F_  = ws + 17039360;      // dbl_bf16 / c_bf16 / cc_bf16 / f_bf16
    float* H_  = ws + 18612224;      // h_bf16 / xc_bf16 / y_bf16 (in place)
    float* J_  = ws + 20709376;      // transposed bf16 weights (8)

    bf16*  xib     = (bf16*)A_;
    bf16*  zb      = xib + (size_t)Mrows*DIc;
    float* part_buf= A_;
    bf16*  c2b     = (bf16*)A_;
    float* P_buf   = A2_;
    float* H_buf   = A2_ + 2097152;
    bf16*  g1b     = (bf16*)B_;
    float* dbl_buf = C_;
    float* dl_buf  = D_;
    float* m_buf   = D_;
    bf16*  dblb    = (bf16*)F_;
    bf16*  cb      = (bf16*)F_;
    bf16*  ccb     = (bf16*)F_;
    bf16*  fb      = (bf16*)F_;
    bf16*  hb      = (bf16*)H_;
    bf16*  xcb     = (bf16*)H_;
    float* f_buf   = out;

    bf16* Jw = (bf16*)J_;
    bf16* Win_t  = Jw;               // 2048 x 512
    bf16* Wx_t   = Jw + 1048576;     //   64 x 1024
    bf16* Wdt_t  = Jw + 1114112;     // 1024 x 32
    bf16* Wout_t = Jw + 1146880;     //  512 x 1024
    bf16* pw1_t  = Jw + 1671168;     // 1024 x 512
    bf16* pw2_t  = Jw + 2195456;     //  512 x 512
    bf16* ffW1_t = Jw + 2457600;     // 2048 x 512
    bf16* ffW2_t = Jw + 3506176;     //  512 x 2048

    const int M = Mrows;

    // 0. merged prep: 8 weight transposes + LN1
    {
        PrepPack p;
        const float* Ws[8] = {W_in, W_x, W_dt, W_out, pw1_w, pw2_w, ff_W1, ff_W2};
        bf16* Ts[8] = {Win_t, Wx_t, Wdt_t, Wout_t, pw1_t, pw2_t, ffW1_t, ffW2_t};
        int Ks[8] = {512, 1024, 32, 1024, 512, 512, 512, 2048};
        int Ns[8] = {2048, 64, 1024, 512, 1024, 512, 2048, 512};
        int acc = 0;
        for (int i = 0; i < 8; ++i) {
            p.W[i] = Ws[i]; p.Wt[i] = Ts[i]; p.K[i] = Ks[i]; p.N[i] = Ns[i];
            p.start[i] = acc;
            acc += (Ns[i]/32)*(Ks[i]/32);
        }
        p.start[8] = acc;            // 4448
        p.lnStart = acc;
        p.x = x; p.lg = ln_g; p.lb = ln_b; p.hb = hb;
        prep_all<<<acc + M, 256, 0, stream>>>(p);
    }

    // 2. xi/z = h @ W_in halves -> bf16 (one launch, grid.z=2; 128x64 tile)
    mgemm<128,64,1,1,0,false,false,false,true><<<dim3(1024/64, M/128, 2), 256, 0, stream>>>(
        hb, Dc, Win_t, nullptr, nullptr, nullptr, xib, M, DIc, Dc);
    // 3. xc = silu(causal dwconv(xi)) -> bf16
    causal_conv_silu<16><<<dim3(DIc/256, Bc, Lc/16), 256, 0, stream>>>(xib, conv_w, conv_b, xcb);
    // 4. dbl = xc @ W_x  (split-K=8 partials -> combine -> f32 + bf16)
    mgemm<64,64,8,0,0,false,false,true,false><<<dim3(64/64, M/64, 8), 256, 0, stream>>>(
        xcb, DIc, Wx_t, nullptr, nullptr, part_buf, nullptr, M, 64, DIc);
    splitk_combine<<<(M*64+255)/256, 256, 0, stream>>>(part_buf, dbl_buf, dblb, M*64, 8);
    // 5. delta = softplus(dt @ W_dt + b_dt) -> f32
    mgemm<64,64,1,0,1,true,false,true,false><<<dim3(1024/64, M/64), 256, 0, stream>>>(
        dblb, 64, Wdt_t, b_dt, nullptr, dl_buf, nullptr, M, DIc, Rc);
    // 6. fused cooperative scan (pass1 + combine + pass3) -> y in place over xcb
    {
        const float* dl_c = dl_buf; bf16* xcy = xcb; const float* dbl_c = dbl_buf;
        const bf16* z_c = zb; const float* al_c = A_log; const float* dp_c = Dp;
        float* P_c = P_buf; float* H_c = H_buf;
        void* args[] = { (void*)&dl_c, (void*)&xcy, (void*)&dbl_c, (void*)&z_c,
                         (void*)&al_c, (void*)&dp_c, (void*)&P_c, (void*)&H_c };
        hipLaunchCooperativeKernel((void*)scan_fused, dim3(512), dim3(256), args, 0, stream);
    }
    // 7. m = y @ W_out -> f32  (wave-split-K, K=1024)
    wgemm<0,0,false,false,true,false><<<dim3(512/64, M/64), 256, 0, stream>>>(
        xcb, DIc, Wout_t, nullptr, nullptr, m_buf, nullptr, M, Dc, DIc);
    // 8. c = LN(m, cm) -> bf16
    ln_kernel<false,true><<<M, 256, 0, stream>>>(m_buf, cm_ln_g, cm_ln_b, nullptr, cb, Dc);
    // 9. c2 = c @ pw1 + b -> bf16 (128x64 tile)
    mgemm<128,64,1,0,0,true,false,false,true><<<dim3(1024/64, M/128), 256, 0, stream>>>(
        cb, Dc, pw1_t, pw1_b, nullptr, nullptr, c2b, M, 2*Dc, Dc);
    // 10+11. GLU fused into symmetric dwconv CK=31 + silu -> bf16
    sym_conv_glu_silu<16><<<dim3(Dc/256, Bc, Lc/16), 256, 0, stream>>>(c2b, dw_w, dw_b, ccb);
    // 12. m = m + (cconv @ pw2 + b) -> f32 in place  (wave-split-K, K=512)
    wgemm<0,0,true,true,true,false><<<dim3(512/64, M/64), 256, 0, stream>>>(
        ccb, Dc, pw2_t, pw2_b, m_buf, m_buf, nullptr, M, Dc, Dc);
    // 13. f = LN(m, ln) -> d_out (f32) + bf16
    ln_kernel<true,true><<<M, 256, 0, stream>>>(m_buf, ln_g, ln_b, f_buf, fb, Dc);
    // 14. g1 = gelu(f @ ff_W1 + b1) -> bf16 (128x64 tile)
    mgemm<128,64,1,0,2,true,false,false,true><<<dim3(2048/64, M/128), 256, 0, stream>>>(
        fb, Dc, ffW1_t, ff_b1, nullptr, nullptr, g1b, M, DFFc, Dc);
    // 15. out = f + g1 @ ff_W2 + b2 -> d_out in place  (wave-split-K, K=2048)
    wgemm<0,0,true,true,true,false><<<dim3(512/64, M/64), 256, 0, stream>>>(
        g1b, DFFc, ffW2_t, ff_b2, f_buf, out, nullptr, M, Dc, DFFc);
}

// Round 14
// 239.944 us; speedup vs baseline: 1.6764x; 1.6764x over previous
//
#include <hip/hip_runtime.h>
#include <hip/hip_bf16.h>
#include <math.h>

// Problem constants
#define Bc   2
#define Lc   2048
#define Dc   512
#define DIc  1024
#define Nc   16
#define Kc   4
#define Rc   32
#define CKc  31
#define DFFc 2048
#define Mrows (Bc*Lc)   // 4096
#define CHUNK  32
#define NCHUNK 64

typedef __hip_bfloat16 bf16;
typedef short bf16x8 __attribute__((ext_vector_type(8)));
typedef float f32x4  __attribute__((ext_vector_type(4)));

__device__ __forceinline__ float sigmoidf_(float x){ return 1.f/(1.f+expf(-x)); }
__device__ __forceinline__ float siluf_(float x){ return x*sigmoidf_(x); }
__device__ __forceinline__ float softplusf_(float x){ return fmaxf(x,0.f)+log1pf(expf(-fabsf(x))); }
__device__ __forceinline__ float geluf_(float x){
    float x3 = x*x*x;
    return 0.5f*x*(1.f+tanhf(0.7978845608028654f*(x+0.044715f*x3)));
}

// async global -> LDS, 16 bytes/lane; lptr is wave-uniform base (HW adds lane*16)
__device__ __forceinline__ void gload16(const void* g, void* l) {
    __builtin_amdgcn_global_load_lds((const __attribute__((address_space(1))) void*)g,
                                     (__attribute__((address_space(3))) void*)l, 16, 0, 0);
}

// ---------------- LayerNorm (one block per row, D=512); optional f32/bf16 outs ----------------
template<bool WF, bool WB>
__global__ void ln_kernel(const float* __restrict__ in, const float* __restrict__ g,
                          const float* __restrict__ bb, float* __restrict__ outf,
                          bf16* __restrict__ outb, int D) {
    int row = blockIdx.x;
    const float* x = in + (size_t)row * D;
    float s = 0.f, s2 = 0.f;
    for (int i = threadIdx.x; i < D; i += blockDim.x) { float v = x[i]; s += v; s2 += v*v; }
    #pragma unroll
    for (int off = 32; off; off >>= 1) { s += __shfl_down(s, off); s2 += __shfl_down(s2, off); }
    __shared__ float sh[2][4];
    int wave = threadIdx.x >> 6, lane = threadIdx.x & 63;
    if (lane == 0) { sh[0][wave] = s; sh[1][wave] = s2; }
    __syncthreads();
    if (threadIdx.x == 0) {
        float ts = 0.f, ts2 = 0.f;
        int nw = blockDim.x >> 6;
        for (int w = 0; w < nw; ++w) { ts += sh[0][w]; ts2 += sh[1][w]; }
        sh[0][0] = ts; sh[1][0] = ts2;
    }
    __syncthreads();
    float mean = sh[0][0] / D;
    float var  = sh[1][0] / D - mean*mean;
    float rstd = rsqrtf(var + 1e-5f);
    for (int i = threadIdx.x; i < D; i += blockDim.x) {
        float v = (x[i]-mean)*rstd*g[i] + bb[i];
        if (WF) outf[(size_t)row*D + i] = v;
        if (WB) outb[(size_t)row*D + i] = __float2bfloat16(v);
    }
}

// ---------------- merged prep: 8 weight transposes + LN1, one launch ----------------
struct PrepPack {
    const float* W[8]; bf16* Wt[8]; int K[8]; int N[8]; int start[9];
    const float* x; const float* lg; const float* lb; bf16* hb;
    int lnStart;
};

__global__ __launch_bounds__(256) void prep_all(PrepPack p) {
    __shared__ float t[32][33];
    __shared__ float sh[2][4];
    int tb = blockIdx.x, tid = threadIdx.x;
    if (tb < p.lnStart) {
        int wi = 0;
        #pragma unroll
        for (int i = 0; i < 7; ++i) if (tb >= p.start[i+1]) wi = i+1;
        int lt = tb - p.start[wi];
        int K = p.K[wi], N = p.N[wi];
        int ntx = N >> 5;
        int bx = lt % ntx, by = lt / ntx;
        const float* W = p.W[wi];
        bf16* Wt = p.Wt[wi];
        int tx = tid & 31, ty = tid >> 5;
        #pragma unroll
        for (int i = 0; i < 32; i += 8)
            t[ty+i][tx] = W[(size_t)(by*32+ty+i)*N + bx*32+tx];
        __syncthreads();
        #pragma unroll
        for (int i = 0; i < 32; i += 8)
            Wt[(size_t)(bx*32+ty+i)*K + by*32+tx] = __float2bfloat16(t[tx][ty+i]);
    } else {
        int row = tb - p.lnStart;
        const float* xr = p.x + (size_t)row * Dc;
        float s = 0.f, s2 = 0.f;
        for (int i = tid; i < Dc; i += 256) { float v = xr[i]; s += v; s2 += v*v; }
        #pragma unroll
        for (int off = 32; off; off >>= 1) { s += __shfl_down(s, off); s2 += __shfl_down(s2, off); }
        int wave = tid >> 6, lane = tid & 63;
        if (lane == 0) { sh[0][wave] = s; sh[1][wave] = s2; }
        __syncthreads();
        if (tid == 0) {
            float ts = 0.f, ts2 = 0.f;
            for (int w = 0; w < 4; ++w) { ts += sh[0][w]; ts2 += sh[1][w]; }
            sh[0][0] = ts; sh[1][0] = ts2;
        }
        __syncthreads();
        float mean = sh[0][0] / Dc;
        float var  = sh[1][0] / Dc - mean*mean;
        float rstd = rsqrtf(var + 1e-5f);
        for (int i = tid; i < Dc; i += 256)
            p.hb[(size_t)row*Dc + i] = __float2bfloat16((xr[i]-mean)*rstd*p.lg[i] + p.lb[i]);
    }
}

// ---------------- bf16 MFMA GEMM, 2-phase dbuf + global_load_lds + XOR swizzle ----------------
// SPLITK>1: grid.z splits K; raw fp32 partials to outf + z*M*N.
// ZSEL=1: grid.z selects weight-half (Wt += z*N*K) and output-half (out += z*M*N).
template<int BM, int BN, int SPLITK, int ZSEL, int ACT, bool BIAS, bool RES, bool WF32, bool WBF16>
__global__ __launch_bounds__(256) void mgemm(const bf16* __restrict__ A, int lda,
                                             const bf16* __restrict__ Wt,
                                             const float* __restrict__ bias,
                                             const float* __restrict__ res,
                                             float* __restrict__ outf,
                                             bf16* __restrict__ outb,
                                             int M, int N, int K) {
    constexpr int BK = 32;
    constexpr int WM = BM/2, WN = BN/2;
    constexpr int AM = WM/16, AN = WN/16;
    constexpr int AISS = BM/64, BISS = BN/64;
    __shared__ __align__(16) bf16 As[2][BM*BK];
    __shared__ __align__(16) bf16 Bs[2][BN*BK];
    const int tid  = threadIdx.x;
    const int wave = tid >> 6, lane = tid & 63;
    const int r16  = lane & 15, kb = lane >> 4;
    const int gx = gridDim.x;
    const int nwg = gx*gridDim.y;
    const int id  = blockIdx.y*gx + blockIdx.x;
    const int sid = (id & 7)*(nwg >> 3) + (id >> 3);
    const int bm = (sid / gx)*BM, bn = (sid % gx)*BN;
    const int wm = (wave>>1)*WM, wn = (wave&1)*WN;
    const bf16* Wp = Wt;
    float* outfp = outf;
    bf16*  outbp = outb;
    if (ZSEL) {
        Wp += (size_t)blockIdx.z*N*K;
        if (WF32)  outfp += (size_t)blockIdx.z*M*N;
        if (WBF16) outbp += (size_t)blockIdx.z*M*N;
    }
    const int Keff = K / SPLITK;
    const int kz0  = (SPLITK > 1) ? blockIdx.z * Keff : 0;
    f32x4 acc[AM][AN] = {};
    const int nt = Keff / BK;

    auto stage = [&](int buf, int kt) {
        #pragma unroll
        for (int it = 0; it < AISS; ++it) {
            int base = (wave*AISS + it) << 10;
            int Lb   = base + (lane << 4);
            int row  = Lb >> 6;
            int gch  = ((Lb >> 4) & 3) ^ (row & 3);
            gload16(A + (size_t)(bm + row)*lda + kz0 + kt*BK + gch*8, (char*)As[buf] + base);
        }
        #pragma unroll
        for (int it = 0; it < BISS; ++it) {
            int base = (wave*BISS + it) << 10;
            int Lb   = base + (lane << 4);
            int row  = Lb >> 6;
            int gch  = ((Lb >> 4) & 3) ^ (row & 3);
            gload16(Wp + (size_t)(bn + row)*K + kz0 + kt*BK + gch*8, (char*)Bs[buf] + base);
        }
    };

    stage(0, 0);
    __syncthreads();
    for (int t = 0; t < nt; ++t) {
        int cur = t & 1;
        if (t + 1 < nt) stage(cur ^ 1, t + 1);
        bf16x8 af[AM], bfr[AN];
        #pragma unroll
        for (int mi = 0; mi < AM; ++mi) {
            int r = wm + mi*16 + r16;
            af[mi] = *(const bf16x8*)((const char*)As[cur] + r*64 + ((kb ^ (r & 3)) << 4));
        }
        #pragma unroll
        for (int ni = 0; ni < AN; ++ni) {
            int r = wn + ni*16 + r16;
            bfr[ni] = *(const bf16x8*)((const char*)Bs[cur] + r*64 + ((kb ^ (r & 3)) << 4));
        }
        #pragma unroll
        for (int mi = 0; mi < AM; ++mi)
            #pragma unroll
            for (int ni = 0; ni < AN; ++ni)
                acc[mi][ni] = __builtin_amdgcn_mfma_f32_16x16x32_bf16(af[mi], bfr[ni], acc[mi][ni], 0, 0, 0);
        __syncthreads();
    }

    #pragma unroll
    for (int mi = 0; mi < AM; ++mi) {
        #pragma unroll
        for (int ni = 0; ni < AN; ++ni) {
            #pragma unroll
            for (int r = 0; r < 4; ++r) {
                int grow = bm + wm + mi*16 + kb*4 + r;
                int gcol = bn + wn + ni*16 + r16;
                float v = acc[mi][ni][r];
                if (SPLITK > 1) {
                    outf[(size_t)blockIdx.z*M*N + (size_t)grow*N + gcol] = v;
                } else {
                    if (BIAS) v += bias[gcol];
                    if (ACT == 1) v = softplusf_(v);
                    else if (ACT == 2) v = geluf_(v);
                    if (RES) v += res[(size_t)grow*N + gcol];
                    if (WF32)  outfp[(size_t)grow*N + gcol] = v;
                    if (WBF16) outbp[(size_t)grow*N + gcol] = __float2bfloat16(v);
                }
            }
        }
    }
}

// ---------------- wave-split-K GEMM: 64x64 tile, 4 waves each own K/4, NO barriers in K-loop ----------------
template<int ZSEL, int ACT, bool BIAS, bool RES, bool WF32, bool WBF16>
__global__ __launch_bounds__(256) void wgemm(const bf16* __restrict__ A, int lda,
                                             const bf16* __restrict__ Wt,
                                             const float* __restrict__ bias,
                                             const float* __restrict__ res,
                                             float* __restrict__ outf,
                                             bf16* __restrict__ outb,
                                             int M, int N, int K) {
    constexpr int BM = 64, BN = 64, BK = 32;
    __shared__ __align__(16) char lds[65536];
    const int tid  = threadIdx.x;
    const int wave = tid >> 6, lane = tid & 63;
    const int r16  = lane & 15, kb = lane >> 4;
    const int gx = gridDim.x;
    const int nwg = gx*gridDim.y;
    const int id  = blockIdx.y*gx + blockIdx.x;
    const int sid = (id & 7)*(nwg >> 3) + (id >> 3);
    const int bm = (sid / gx)*BM, bn = (sid % gx)*BN;
    const bf16* Wp = Wt;
    float* outfp = outf;
    bf16*  outbp = outb;
    const float* resp = res;
    if (ZSEL) {
        Wp += (size_t)blockIdx.z*N*K;
        if (WF32)  outfp += (size_t)blockIdx.z*M*N;
        if (WBF16) outbp += (size_t)blockIdx.z*M*N;
    }
    const int Kw  = K >> 2;
    const int k0w = wave * Kw;
    const int nt  = Kw / BK;
    char* myL = lds + wave*16384;
    f32x4 acc[4][4] = {};

    auto stage = [&](int buf, int kt) {
        #pragma unroll
        for (int it = 0; it < 4; ++it) {
            int base = it << 10;
            int Lb   = base + (lane << 4);
            int row  = Lb >> 6;
            int gch  = ((Lb >> 4) & 3) ^ (row & 3);
            gload16(A + (size_t)(bm + row)*lda + k0w + kt*BK + gch*8, myL + buf*8192 + base);
        }
        #pragma unroll
        for (int it = 0; it < 4; ++it) {
            int base = it << 10;
            int Lb   = base + (lane << 4);
            int row  = Lb >> 6;
            int gch  = ((Lb >> 4) & 3) ^ (row & 3);
            gload16(Wp + (size_t)(bn + row)*K + k0w + kt*BK + gch*8, myL + buf*8192 + 4096 + base);
        }
    };

    stage(0, 0);
    for (int t = 0; t < nt; ++t) {
        int cur = t & 1;
        if (t + 1 < nt) {
            stage(cur ^ 1, t + 1);
            asm volatile("s_waitcnt vmcnt(8)" ::: "memory");
        } else {
            asm volatile("s_waitcnt vmcnt(0)" ::: "memory");
        }
        __builtin_amdgcn_sched_barrier(0);
        const char* bufA = myL + cur*8192;
        const char* bufB = bufA + 4096;
        bf16x8 af[4], bfr[4];
        #pragma unroll
        for (int mi = 0; mi < 4; ++mi) {
            int r = mi*16 + r16;
            af[mi] = *(const bf16x8*)(bufA + r*64 + ((kb ^ (r & 3)) << 4));
        }
        #pragma unroll
        for (int ni = 0; ni < 4; ++ni) {
            int r = ni*16 + r16;
            bfr[ni] = *(const bf16x8*)(bufB + r*64 + ((kb ^ (r & 3)) << 4));
        }
        #pragma unroll
        for (int mi = 0; mi < 4; ++mi)
            #pragma unroll
            for (int ni = 0; ni < 4; ++ni)
                acc[mi][ni] = __builtin_amdgcn_mfma_f32_16x16x32_bf16(af[mi], bfr[ni], acc[mi][ni], 0, 0, 0);
    }

    __syncthreads();
    float* red = (float*)lds;
    #pragma unroll
    for (int mi = 0; mi < 4; ++mi) {
        #pragma unroll
        for (int ni = 0; ni < 4; ++ni) {
            int row0 = mi*16 + kb*4;
            int col  = ni*16 + r16;
            #pragma unroll
            for (int r = 0; r < 4; ++r)
                red[wave*4096 + (row0+r)*64 + col] = acc[mi][ni][r];
        }
    }
    __syncthreads();
    #pragma unroll
    for (int i = 0; i < 16; ++i) {
        int o = i*256 + tid;
        int row = o >> 6, col = o & 63;
        float v = red[o] + red[4096+o] + red[8192+o] + red[12288+o];
        int grow = bm + row, gcol = bn + col;
        if (BIAS) v += bias[gcol];
        if (ACT == 1) v = softplusf_(v);
        else if (ACT == 2) v = geluf_(v);
        if (RES) v += resp[(size_t)grow*N + gcol];
        if (WF32)  outfp[(size_t)grow*N + gcol] = v;
        if (WBF16) outbp[(size_t)grow*N + gcol] = __float2bfloat16(v);
    }
}

// sum SPLITK partials -> f32 + bf16
__global__ void splitk_combine(const float* __restrict__ part, float* __restrict__ outf,
                               bf16* __restrict__ outb, int n, int parts) {
    int i = blockIdx.x*256 + threadIdx.x;
    if (i >= n) return;
    float s = 0.f;
    for (int p = 0; p < parts; ++p) s += part[(size_t)p*n + i];
    outf[i] = s;
    outb[i] = __float2bfloat16(s);
}

// ---------------- causal depthwise conv K=4 + silu (bf16 in) -> bf16, sliding-window regs ----------------
template<int T>
__global__ __launch_bounds__(256) void causal_conv_silu(const bf16* __restrict__ xi, const float* __restrict__ w,
                                                        const float* __restrict__ bias,
                                                        bf16* __restrict__ xcb) {
    int d  = blockIdx.x*256 + threadIdx.x;
    int b  = blockIdx.y;
    int l0 = blockIdx.z*T;
    const bf16* src = xi + (size_t)b*Lc*DIc + d;
    float wt[Kc];
    #pragma unroll
    for (int k = 0; k < Kc; ++k) wt[k] = w[d*Kc + k];
    float win[T + Kc - 1];
    #pragma unroll
    for (int i = 0; i < T + Kc - 1; ++i) {
        int li = l0 - (Kc-1) + i;
        win[i] = (li >= 0) ? __bfloat162float(src[(size_t)li*DIc]) : 0.f;
    }
    float bv = bias[d];
    size_t obase = (size_t)b*Lc*DIc + (size_t)l0*DIc + d;
    #pragma unroll
    for (int o = 0; o < T; ++o) {
        float acc = bv;
        #pragma unroll
        for (int k = 0; k < Kc; ++k) acc = fmaf(win[o+k], wt[k], acc);
        xcb[obase + (size_t)o*DIc] = __float2bfloat16(siluf_(acc));
    }
}

// ---------------- chunked selective scan, thread-per-channel, 16 states in registers ----------------
__global__ __launch_bounds__(256) void scan_pass1(const float* __restrict__ delta, const bf16* __restrict__ xc,
                                                  const float* __restrict__ dbl, const float* __restrict__ A_log,
                                                  float* __restrict__ P, float* __restrict__ H) {
    int dgroup = blockIdx.x & 3;
    int bci = blockIdx.x >> 2;
    int b = bci & 1, chunk = bci >> 1;
    int d = dgroup*256 + threadIdx.x;
    float Av[16];
    #pragma unroll
    for (int j = 0; j < 4; ++j) {
        f32x4 v = *(const f32x4*)(&A_log[d*16 + 4*j]);
        #pragma unroll
        for (int q = 0; q < 4; ++q) Av[4*j+q] = -__expf(v[q]);
    }
    float h[16], Pl[16];
    #pragma unroll
    for (int n = 0; n < 16; ++n) { h[n] = 0.f; Pl[n] = 1.f; }
    size_t row0 = (size_t)b*Lc + (size_t)chunk*CHUNK;
    for (int i = 0; i < CHUNK; ++i) {
        size_t rowi = row0 + i;
        float dv  = delta[rowi*DIc + d];
        float xcv = __bfloat162float(xc[rowi*DIc + d]);
        float dxc = dv*xcv;
        f32x4 B0 = *(const f32x4*)(&dbl[rowi*64 + Rc + 0]);
        f32x4 B1 = *(const f32x4*)(&dbl[rowi*64 + Rc + 4]);
        f32x4 B2 = *(const f32x4*)(&dbl[rowi*64 + Rc + 8]);
        f32x4 B3 = *(const f32x4*)(&dbl[rowi*64 + Rc + 12]);
        float Bv[16];
        #pragma unroll
        for (int q = 0; q < 4; ++q) { Bv[q]=B0[q]; Bv[4+q]=B1[q]; Bv[8+q]=B2[q]; Bv[12+q]=B3[q]; }
        #pragma unroll
        for (int n = 0; n < 16; ++n) {
            float a = __expf(dv*Av[n]);
            h[n] = fmaf(a, h[n], dxc*Bv[n]);
            Pl[n] *= a;
        }
    }
    size_t pidx = ((size_t)chunk*2048 + (size_t)b*DIc + d) * 16;
    #pragma unroll
    for (int j = 0; j < 4; ++j) {
        f32x4 vp, vh;
        #pragma unroll
        for (int q = 0; q < 4; ++q) { vp[q] = Pl[4*j+q]; vh[q] = h[4*j+q]; }
        *(f32x4*)(&P[pidx + 4*j]) = vp;
        *(f32x4*)(&H[pidx + 4*j]) = vh;
    }
}

__global__ void scan_combine(float* __restrict__ P, const float* __restrict__ H) {
    int t = blockIdx.x*blockDim.x + threadIdx.x;
    float h = 0.f;
    #pragma unroll
    for (int c = 0; c < NCHUNK; ++c) {
        size_t idx = (size_t)c*32768 + t;
        float Pv = P[idx], Hv = H[idx];
        P[idx] = h;
        h = fmaf(Pv, h, Hv);
    }
}

__global__ __launch_bounds__(256) void scan_pass3(const float* __restrict__ delta, const bf16* __restrict__ xc,
                                                  const float* __restrict__ dbl, const bf16* __restrict__ z,
                                                  const float* __restrict__ A_log, const float* __restrict__ Dp,
                                                  const float* __restrict__ hstart, bf16* __restrict__ y) {
    int dgroup = blockIdx.x & 3;
    int bci = blockIdx.x >> 2;
    int b = bci & 1, chunk = bci >> 1;
    int d = dgroup*256 + threadIdx.x;
    float Av[16];
    #pragma unroll
    for (int j = 0; j < 4; ++j) {
        f32x4 v = *(const f32x4*)(&A_log[d*16 + 4*j]);
        #pragma unroll
        for (int q = 0; q < 4; ++q) Av[4*j+q] = -__expf(v[q]);
    }
    float Dv = Dp[d];
    float h[16];
    size_t pidx = ((size_t)chunk*2048 + (size_t)b*DIc + d) * 16;
    #pragma unroll
    for (int j = 0; j < 4; ++j) {
        f32x4 v = *(const f32x4*)(&hstart[pidx + 4*j]);
        #pragma unroll
        for (int q = 0; q < 4; ++q) h[4*j+q] = v[q];
    }
    size_t row0 = (size_t)b*Lc + (size_t)chunk*CHUNK;
    for (int i = 0; i < CHUNK; ++i) {
        size_t rowi = row0 + i;
        float dv  = delta[rowi*DIc + d];
        float xcv = __bfloat162float(xc[rowi*DIc + d]);
        float dxc = dv*xcv;
        f32x4 B0 = *(const f32x4*)(&dbl[rowi*64 + Rc + 0]);
        f32x4 B1 = *(const f32x4*)(&dbl[rowi*64 + Rc + 4]);
        f32x4 B2 = *(const f32x4*)(&dbl[rowi*64 + Rc + 8]);
        f32x4 B3 = *(const f32x4*)(&dbl[rowi*64 + Rc + 12]);
        f32x4 C0 = *(const f32x4*)(&dbl[rowi*64 + Rc + Nc + 0]);
        f32x4 C1 = *(const f32x4*)(&dbl[rowi*64 + Rc + Nc + 4]);
        f32x4 C2 = *(const f32x4*)(&dbl[rowi*64 + Rc + Nc + 8]);
        f32x4 C3 = *(const f32x4*)(&dbl[rowi*64 + Rc + Nc + 12]);
        float Bv[16], Cv[16];
        #pragma unroll
        for (int q = 0; q < 4; ++q) {
            Bv[q]=B0[q]; Bv[4+q]=B1[q]; Bv[8+q]=B2[q]; Bv[12+q]=B3[q];
            Cv[q]=C0[q]; Cv[4+q]=C1[q]; Cv[8+q]=C2[q]; Cv[12+q]=C3[q];
        }
        float s0=0.f, s1=0.f, s2=0.f, s3=0.f;
        #pragma unroll
        for (int n = 0; n < 16; ++n) {
            float a = __expf(dv*Av[n]);
            h[n] = fmaf(a, h[n], dxc*Bv[n]);
        }
        #pragma unroll
        for (int j = 0; j < 4; ++j) {
            s0 = fmaf(h[4*j+0], Cv[4*j+0], s0);
            s1 = fmaf(h[4*j+1], Cv[4*j+1], s1);
            s2 = fmaf(h[4*j+2], Cv[4*j+2], s2);
            s3 = fmaf(h[4*j+3], Cv[4*j+3], s3);
        }
        float contrib = (s0+s1)+(s2+s3);
        float zv = __bfloat162float(z[rowi*DIc + d]);
        y[rowi*DIc + d] = __float2bfloat16((contrib + Dv*xcv) * siluf_(zv));
    }
}

// ---------------- fused GLU + symmetric depthwise conv CK=31 + silu (bf16 in) -> bf16 ----------------
template<int T>
__global__ __launch_bounds__(256) void sym_conv_glu_silu(const bf16* __restrict__ c2, const float* __restrict__ w,
                                                         const float* __restrict__ bias, bf16* __restrict__ out) {
    int d  = blockIdx.x*256 + threadIdx.x;
    int b  = blockIdx.y;
    int l0 = blockIdx.z*T;
    const bf16* base = c2 + (size_t)b*Lc*(2*Dc) + d;
    float wt[CKc];
    #pragma unroll
    for (int k = 0; k < CKc; ++k) wt[k] = w[d*CKc + k];
    constexpr int HALF = (CKc-1)/2;
    float win[T + CKc - 1];
    #pragma unroll
    for (int i = 0; i < T + CKc - 1; ++i) {
        int li = l0 - HALF + i;
        if (li >= 0 && li < Lc) {
            float a = __bfloat162float(base[(size_t)li*(2*Dc)]);
            float g = __bfloat162float(base[(size_t)li*(2*Dc) + Dc]);
            win[i] = a * sigmoidf_(g);
        } else win[i] = 0.f;
    }
    float bv = bias[d];
    size_t obase = (size_t)b*Lc*Dc + (size_t)l0*Dc + d;
    #pragma unroll
    for (int o = 0; o < T; ++o) {
        float acc = bv;
        #pragma unroll
        for (int k = 0; k < CKc; ++k) acc = fmaf(win[o+k], wt[k], acc);
        out[obase + (size_t)o*Dc] = __float2bfloat16(siluf_(acc));
    }
}

extern "C" void kernel_launch(void* const* d_in, const int* in_sizes, int n_in,
                              void* d_out, int out_size, void* d_ws, size_t ws_size,
                              hipStream_t stream) {
    const float* x      = (const float*)d_in[0];
    const float* ln_g   = (const float*)d_in[1];
    const float* ln_b   = (const float*)d_in[2];
    const float* W_in   = (const float*)d_in[3];
    const float* conv_w = (const float*)d_in[4];
    const float* conv_b = (const float*)d_in[5];
    const float* W_x    = (const float*)d_in[6];
    const float* W_dt   = (const float*)d_in[7];
    const float* b_dt   = (const float*)d_in[8];
    const float* A_log  = (const float*)d_in[9];
    const float* Dp     = (const float*)d_in[10];
    const float* W_out  = (const float*)d_in[11];
    const float* cm_ln_g= (const float*)d_in[12];
    const float* cm_ln_b= (const float*)d_in[13];
    const float* pw1_w  = (const float*)d_in[14];
    const float* pw1_b  = (const float*)d_in[15];
    const float* dw_w   = (const float*)d_in[16];
    const float* dw_b   = (const float*)d_in[17];
    const float* pw2_w  = (const float*)d_in[18];
    const float* pw2_b  = (const float*)d_in[19];
    const float* ff_W1  = (const float*)d_in[20];
    const float* ff_b1  = (const float*)d_in[21];
    const float* ff_W2  = (const float*)d_in[22];
    const float* ff_b2  = (const float*)d_in[23];
    float* out = (float*)d_out;
    float* ws  = (float*)d_ws;

    // ---- workspace layout (float offsets) ----
    float* A_  = ws;                 // xi_bf16+z_bf16 (16MB) -> part(2M fl)/c2_bf16
    float* A2_ = ws + 4194304;       // P (2M) + H (2M)
    float* B_  = ws + 8388608;       // g1_bf16
    float* C_  = ws + 12582912;      // dbl f32 (M x 64)
    float* D_  = ws + 12845056;      // delta -> m (2M)
    float* F_  = ws + 17039360;      // dbl_bf16 / c_bf16 / cc_bf16 / f_bf16
    float* H_  = ws + 18612224;      // h_bf16 / xc_bf16 / y_bf16 (in place)
    float* J_  = ws + 20709376;      // transposed bf16 weights (8)

    bf16*  xib     = (bf16*)A_;
    bf16*  zb      = xib + (size_t)Mrows*DIc;
    float* part_buf= A_;
    bf16*  c2b     = (bf16*)A_;
    float* P_buf   = A2_;
    float* H_buf   = A2_ + 2097152;
    bf16*  g1b     = (bf16*)B_;
    float* dbl_buf = C_;
    float* dl_buf  = D_;
    float* m_buf   = D_;
    bf16*  dblb    = (bf16*)F_;
    bf16*  cb      = (bf16*)F_;
    bf16*  ccb     = (bf16*)F_;
    bf16*  fb      = (bf16*)F_;
    bf16*  hb      = (bf16*)H_;
    bf16*  xcb     = (bf16*)H_;
    bf16*  yb      = (bf16*)H_;
    float* f_buf   = out;

    bf16* Jw = (bf16*)J_;
    bf16* Win_t  = Jw;               // 2048 x 512
    bf16* Wx_t   = Jw + 1048576;     //   64 x 1024
    bf16* Wdt_t  = Jw + 1114112;     // 1024 x 32
    bf16* Wout_t = Jw + 1146880;     //  512 x 1024
    bf16* pw1_t  = Jw + 1671168;     // 1024 x 512
    bf16* pw2_t  = Jw + 2195456;     //  512 x 512
    bf16* ffW1_t = Jw + 2457600;     // 2048 x 512
    bf16* ffW2_t = Jw + 3506176;     //  512 x 2048

    const int M = Mrows;

    // 0. merged prep: 8 weight transposes + LN1
    {
        PrepPack p;
        const float* Ws[8] = {W_in, W_x, W_dt, W_out, pw1_w, pw2_w, ff_W1, ff_W2};
        bf16* Ts[8] = {Win_t, Wx_t, Wdt_t, Wout_t, pw1_t, pw2_t, ffW1_t, ffW2_t};
        int Ks[8] = {512, 1024, 32, 1024, 512, 512, 512, 2048};
        int Ns[8] = {2048, 64, 1024, 512, 1024, 512, 2048, 512};
        int acc = 0;
        for (int i = 0; i < 8; ++i) {
            p.W[i] = Ws[i]; p.Wt[i] = Ts[i]; p.K[i] = Ks[i]; p.N[i] = Ns[i];
            p.start[i] = acc;
            acc += (Ns[i]/32)*(Ks[i]/32);
        }
        p.start[8] = acc;            // 4448
        p.lnStart = acc;
        p.x = x; p.lg = ln_g; p.lb = ln_b; p.hb = hb;
        prep_all<<<acc + M, 256, 0, stream>>>(p);
    }

    // 2. xi/z = h @ W_in halves -> bf16 (one launch, grid.z=2; 128x64 tile)
    mgemm<128,64,1,1,0,false,false,false,true><<<dim3(1024/64, M/128, 2), 256, 0, stream>>>(
        hb, Dc, Win_t, nullptr, nullptr, nullptr, xib, M, DIc, Dc);
    // 3. xc = silu(causal dwconv(xi)) -> bf16
    causal_conv_silu<16><<<dim3(DIc/256, Bc, Lc/16), 256, 0, stream>>>(xib, conv_w, conv_b, xcb);
    // 4. dbl = xc @ W_x  (split-K=8 partials -> combine -> f32 + bf16)
    mgemm<64,64,8,0,0,false,false,true,false><<<dim3(64/64, M/64, 8), 256, 0, stream>>>(
        xcb, DIc, Wx_t, nullptr, nullptr, part_buf, nullptr, M, 64, DIc);
    splitk_combine<<<(M*64+255)/256, 256, 0, stream>>>(part_buf, dbl_buf, dblb, M*64, 8);
    // 5. delta = softplus(dt @ W_dt + b_dt) -> f32
    mgemm<64,64,1,0,1,true,false,true,false><<<dim3(1024/64, M/64), 256, 0, stream>>>(
        dblb, 64, Wdt_t, b_dt, nullptr, dl_buf, nullptr, M, DIc, Rc);
    // 6. chunked selective scan -> y (bf16, in place over xcb)
    scan_pass1<<<512, 256, 0, stream>>>(dl_buf, xcb, dbl_buf, A_log, P_buf, H_buf);
    scan_combine<<<128, 256, 0, stream>>>(P_buf, H_buf);
    scan_pass3<<<512, 256, 0, stream>>>(dl_buf, xcb, dbl_buf, zb, A_log, Dp, P_buf, yb);
    // 7. m = y @ W_out -> f32  (wave-split-K, K=1024)
    wgemm<0,0,false,false,true,false><<<dim3(512/64, M/64), 256, 0, stream>>>(
        yb, DIc, Wout_t, nullptr, nullptr, m_buf, nullptr, M, Dc, DIc);
    // 8. c = LN(m, cm) -> bf16
    ln_kernel<false,true><<<M, 256, 0, stream>>>(m_buf, cm_ln_g, cm_ln_b, nullptr, cb, Dc);
    // 9. c2 = c @ pw1 + b -> bf16 (128x64 tile)
    mgemm<128,64,1,0,0,true,false,false,true><<<dim3(1024/64, M/128), 256, 0, stream>>>(
        cb, Dc, pw1_t, pw1_b, nullptr, nullptr, c2b, M, 2*Dc, Dc);
    // 10+11. GLU fused into symmetric dwconv CK=31 + silu -> bf16
    sym_conv_glu_silu<16><<<dim3(Dc/256, Bc, Lc/16), 256, 0, stream>>>(c2b, dw_w, dw_b, ccb);
    // 12. m = m + (cconv @ pw2 + b) -> f32 in place  (wave-split-K, K=512)
    wgemm<0,0,true,true,true,false><<<dim3(512/64, M/64), 256, 0, stream>>>(
        ccb, Dc, pw2_t, pw2_b, m_buf, m_buf, nullptr, M, Dc, Dc);
    // 13. f = LN(m, ln) -> d_out (f32) + bf16
    ln_kernel<true,true><<<M, 256, 0, stream>>>(m_buf, ln_g, ln_b, f_buf, fb, Dc);
    // 14. g1 = gelu(f @ ff_W1 + b1) -> bf16 (128x64 tile)
    mgemm<128,64,1,0,2,true,false,false,true><<<dim3(2048/64, M/128), 256, 0, stream>>>(
        fb, Dc, ffW1_t, ff_b1, nullptr, nullptr, g1b, M, DFFc, Dc);
    // 15. out = f + g1 @ ff_W2 + b2 -> d_out in place  (wave-split-K, K=2048)
    wgemm<0,0,true,true,true,false><<<dim3(512/64, M/64), 256, 0, stream>>>(
        g1b, DFFc, ffW2_t, ff_b2, f_buf, out, nullptr, M, Dc, DFFc);
}